// Round 5
// baseline (73.955 us; speedup 1.0000x reference)
//
#include <hip/hip_runtime.h>

// out[i, 7n+o, m] = sum_{j,k} x[j, 7n+o+k-1, m] * W[i,j,k], taps clipped to o+k-1 in [0,7)
// x: (48,56,56) f32, W: (192,48,3) f32, out: (192,56,56) f32
//
// R5: LDS-staged. Block(128) owns (n-block, 3 output channels).
// Stage x n-block slice (48j x 98 float4, contiguous per j) into LDS in 2 passes
// of 24 j; compute reads LDS only. Rows padded +-14 positions with zeros so
// boundary taps are unconditional. W pre-transposed to float4 (3 i's packed).
// Grid = 8 n * 64 igroups = 512 blocks = exactly 2 per CU.

#define SP4 784        // 3136 floats / 4 : float4 per input channel
#define POS 98         // 7 rows * 56 cols / 4 : float4 positions per n-block
#define PADPOS 128     // 14 zero-pad + 98 + 16 zero-pad (pow2 for cheap indexing)
#define JP 24          // j-channels staged per pass
#define NPASS 2
#define IG 3           // output channels per block (192/64)
#define WSTRIDE 144    // 48*3 floats per W output-channel row

__device__ __forceinline__ void fma4(float4& a, float s, const float4& b) {
    a.x += s * b.x; a.y += s * b.y; a.z += s * b.z; a.w += s * b.w;
}

__global__ __launch_bounds__(128) void conv_lds_kernel(const float* __restrict__ x,
                                                       const float* __restrict__ W,
                                                       float* __restrict__ out) {
    __shared__ float4 X[JP][PADPOS];   // 48 KB
    __shared__ float4 WT[JP][3];       // 1.125 KB  WT[j][k] = {W[i0+0], W[i0+1], W[i0+2], 0}

    const int tid = threadIdx.x;
    const int n   = blockIdx.x & 7;          // n-block
    const int ig  = blockIdx.x >> 3;         // i-group [0,64)
    const int i0  = ig * IG;

    const float4* gx = (const float4*)x + n * POS;   // + j*SP4 per channel

    float4 acc[IG];
#pragma unroll
    for (int d = 0; d < IG; ++d) acc[d] = make_float4(0.f, 0.f, 0.f, 0.f);

    for (int pass = 0; pass < NPASS; ++pass) {
        const int jb = pass * JP;
        __syncthreads();   // protect LDS from overwrite while prior pass computes

        // Stage x: 24 j-rows of 128 padded float4 positions (3072 elems, 24 iters)
        for (int idx = tid; idx < JP * PADPOS; idx += 128) {
            const int j  = idx >> 7;
            const int pp = idx & 127;
            float4 v = make_float4(0.f, 0.f, 0.f, 0.f);
            if (pp >= 14 && pp < 14 + POS)
                v = gx[(jb + j) * SP4 + (pp - 14)];
            X[j][pp] = v;
        }
        // Stage W transposed: 72 float4
        if (tid < JP * 3) {
            const int j = tid / 3;
            const int k = tid % 3;
            float4 w;
            w.x = W[(i0 + 0) * WSTRIDE + (jb + j) * 3 + k];
            w.y = W[(i0 + 1) * WSTRIDE + (jb + j) * 3 + k];
            w.z = W[(i0 + 2) * WSTRIDE + (jb + j) * 3 + k];
            w.w = 0.f;
            WT[j][k] = w;
        }
        __syncthreads();

        if (tid < POS) {
#pragma unroll 4
            for (int j = 0; j < JP; ++j) {
                const float4 xm = X[j][tid];        // row o-1 (zero-padded)
                const float4 x0 = X[j][tid + 14];   // row o
                const float4 xp = X[j][tid + 28];   // row o+1 (zero-padded)
                const float4 w0 = WT[j][0];
                const float4 w1 = WT[j][1];
                const float4 w2 = WT[j][2];
                fma4(acc[0], w0.x, xm); fma4(acc[0], w1.x, x0); fma4(acc[0], w2.x, xp);
                fma4(acc[1], w0.y, xm); fma4(acc[1], w1.y, x0); fma4(acc[1], w2.y, xp);
                fma4(acc[2], w0.z, xm); fma4(acc[2], w1.z, x0); fma4(acc[2], w2.z, xp);
            }
        }
    }

    if (tid < POS) {
        float4* gout = (float4*)out + n * POS + tid;
#pragma unroll
        for (int d = 0; d < IG; ++d)
            gout[(i0 + d) * SP4] = acc[d];
    }
}

extern "C" void kernel_launch(void* const* d_in, const int* in_sizes, int n_in,
                              void* d_out, int out_size, void* d_ws, size_t ws_size,
                              hipStream_t stream) {
    const float* x = (const float*)d_in[0];
    const float* W = (const float*)d_in[1];
    float* out = (float*)d_out;

    conv_lds_kernel<<<512, 128, 0, stream>>>(x, W, out);  // 8 n * 64 igroups
}

// Round 6
// 60.695 us; speedup vs baseline: 1.2185x; 1.2185x over previous
//
#include <hip/hip_runtime.h>

// out[i, 7n+o, m] = sum_{j,k} x[j, 7n+o+k-1, m] * W[i,j,k], taps clipped to o+k-1 in [0,7)
// x: (48,56,56) f32, W: (192,48,3) f32, out: (192,56,56) f32
//
// R6: R4 shape + 4-channel register reuse. Thread = (igroup of 4 i, column, j-seg).
// Each xv load feeds 4 channels' FMAs -> x traffic 116 MB -> 29 MB.
// Block = 128 thr = 8 cols x 16 segs (JSEG=3). Grid = 48 igroups x 14 colgroups = 672.
// Epilogue: LDS reduce of 16 segs, two phases of 2 channels (32 KB, pad +1 float4).

#define CH_IN 48
#define CH_OUT 192
#define HW 56
#define SP 3136   // 56*56
#define OB 7      // rows per n-block
#define M4 14     // float4 chunks per 56-wide row
#define COLS 112  // spatial columns per channel
#define SEGS 16
#define JSEG 3    // 48/16
#define BCOL 8    // columns per block
#define IG 4      // output channels per thread
#define CG 14     // colgroups per channel (112/8)
#define WST 144   // 48*3 floats per W row

__device__ __forceinline__ void fma4(float4& a, float s, const float4& b) {
    a.x += s * b.x; a.y += s * b.y; a.z += s * b.z; a.w += s * b.w;
}
__device__ __forceinline__ void add4(float4& a, const float4& b) {
    a.x += b.x; a.y += b.y; a.z += b.z; a.w += b.w;
}

__global__ __launch_bounds__(128, 2) void conv_ig4_kernel(const float* __restrict__ x,
                                                          const float* __restrict__ W,
                                                          float* __restrict__ out) {
    __shared__ float4 red[SEGS][2][OB][BCOL + 1];   // 32.25 KB (pad breaks seg-stride aliasing)

    const int tid = threadIdx.x;
    const int c   = tid & (BCOL - 1);      // column within block [0,8)
    const int seg = tid >> 3;              // j-segment [0,16)
    const int ig4 = blockIdx.x / CG;       // i-group [0,48)
    const int cg  = blockIdx.x % CG;       // colgroup [0,14)
    const int i0  = ig4 * IG;

    const int col = cg * BCOL + c;         // [0,112)
    const int n   = col / M4;
    const int m4  = col % M4;

    const float* xcol  = x + seg * (JSEG * SP) + n * (OB * HW) + m4 * 4;
    const float* wbase = W + i0 * WST + seg * (JSEG * 3);

    float4 acc[IG][OB];
#pragma unroll
    for (int ig = 0; ig < IG; ++ig)
#pragma unroll
        for (int o = 0; o < OB; ++o) acc[ig][o] = make_float4(0.f, 0.f, 0.f, 0.f);

#pragma unroll
    for (int j = 0; j < JSEG; ++j) {
        const float* xj = xcol + j * SP;
        float4 xv[OB];
#pragma unroll
        for (int o = 0; o < OB; ++o)
            xv[o] = *reinterpret_cast<const float4*>(xj + o * HW);

#pragma unroll
        for (int ig = 0; ig < IG; ++ig) {
            const float* wp = wbase + ig * WST + j * 3;
            const float w0 = wp[0];
            const float w1 = wp[1];
            const float w2 = wp[2];
#pragma unroll
            for (int o = 0; o < OB; ++o) {
                if (o > 0)      fma4(acc[ig][o], w0, xv[o - 1]);  // k=0 tap
                fma4(acc[ig][o], w1, xv[o]);                      // k=1 tap
                if (o < OB - 1) fma4(acc[ig][o], w2, xv[o + 1]);  // k=2 tap
            }
        }
    }

    // Reduce 16 segments; two phases of 2 output channels each.
#pragma unroll
    for (int p = 0; p < 2; ++p) {
        __syncthreads();   // safe LDS reuse across phases
#pragma unroll
        for (int d = 0; d < 2; ++d)
#pragma unroll
            for (int o = 0; o < OB; ++o)
                red[seg][d][o][c] = acc[2 * p + d][o];
        __syncthreads();

        if (tid < 2 * OB * BCOL) {   // 112 reducers
            const int d  = tid / (OB * BCOL);
            const int r  = tid % (OB * BCOL);
            const int o  = r / BCOL;
            const int cc = r % BCOL;
            float4 s = red[0][d][o][cc];
#pragma unroll
            for (int sg = 1; sg < SEGS; ++sg) add4(s, red[sg][d][o][cc]);

            const int col2 = cg * BCOL + cc;
            const int n2   = col2 / M4;
            const int m42  = col2 % M4;
            *reinterpret_cast<float4*>(out + (i0 + 2 * p + d) * SP + n2 * (OB * HW) + o * HW + m42 * 4) = s;
        }
    }
}

extern "C" void kernel_launch(void* const* d_in, const int* in_sizes, int n_in,
                              void* d_out, int out_size, void* d_ws, size_t ws_size,
                              hipStream_t stream) {
    const float* x = (const float*)d_in[0];
    const float* W = (const float*)d_in[1];
    float* out = (float*)d_out;

    const int grid = (CH_OUT / IG) * CG;  // 672 blocks x 128 threads
    conv_ig4_kernel<<<grid, 128, 0, stream>>>(x, W, out);
}